// Round 3
// baseline (1558.734 us; speedup 1.0000x reference)
//
#include <hip/hip_runtime.h>
#include <stddef.h>

#define K_CB   2048
#define C_DIM  64
#define HW_DIM 3136
#define B_DIM  8
#define TR     16

static const size_t OUT_FEAT_SZ = (size_t)B_DIM * C_DIM * HW_DIM;  // 1605632
static const size_t ASSIGN_SZ   = (size_t)B_DIM * K_CB * HW_DIM;   // 51380224
static const size_t DIST_SZ     = (size_t)B_DIM * HW_DIM * K_CB;   // 51380224

// ---------------------------------------------------------------------------
// Kernel A: codebook norms + transpose cbT[c][k] + zero vq0. grid = 8 x 256.
// ---------------------------------------------------------------------------
__global__ __launch_bounds__(256) void vq_prep(const float* __restrict__ cb,
                                               float* __restrict__ cbT,
                                               float* __restrict__ cnorm,
                                               float* __restrict__ vq0) {
    const int k = blockIdx.x * 256 + threadIdx.x;
    const float4* row = reinterpret_cast<const float4*>(cb + (size_t)k * C_DIM);
    float n = 0.f;
#pragma unroll
    for (int i = 0; i < 16; ++i) {
        float4 v = row[i];
        n = fmaf(v.x, v.x, n); n = fmaf(v.y, v.y, n);
        n = fmaf(v.z, v.z, n); n = fmaf(v.w, v.w, n);
        cbT[(size_t)(4 * i + 0) * K_CB + k] = v.x;
        cbT[(size_t)(4 * i + 1) * K_CB + k] = v.y;
        cbT[(size_t)(4 * i + 2) * K_CB + k] = v.z;
        cbT[(size_t)(4 * i + 3) * K_CB + k] = v.w;
    }
    cnorm[k] = n;
    vq0[k] = 0.f;
}

// ---------------------------------------------------------------------------
// Kernel B: distance + argmin/histogram + softmax + prob write.
// 512 threads, 16 pixels/WG. Thread owns 4 CONSECUTIVE k (k=4t..4t+3):
// cw is one dwordx4 load, dist row store is one dwordx4 (1KB/wave).
// launch_bounds(512,4) -> VGPR cap 128 -> 2 blocks/CU (16 waves).
// ---------------------------------------------------------------------------
__global__ __launch_bounds__(512, 4) void vq_main(const float* __restrict__ feat,
                                                  const float* __restrict__ cbT,
                                                  const float* __restrict__ cnorm,
                                                  float* __restrict__ dist,
                                                  float* __restrict__ assign,
                                                  float* __restrict__ vq0) {
    const int t   = threadIdx.x;
    const int n0  = blockIdx.x * TR;
    const int b   = n0 / HW_DIM;
    const int hw0 = n0 % HW_DIM;

    __shared__ float flatT[C_DIM][TR];
    __shared__ float fnorm_s[TR];
    __shared__ float m_s[TR];
    __shared__ float zinv_s[TR];
    __shared__ unsigned long long redmin[TR][8];
    __shared__ float redsum[TR][8];

#pragma unroll
    for (int i = 0; i < 2; ++i) {
        int idx = t + 512 * i;
        int c = idx >> 4, r = idx & 15;
        flatT[c][r] = feat[((size_t)b * C_DIM + c) * HW_DIM + hw0 + r];
    }
    __syncthreads();
    if (t < TR) {
        float s = 0.f;
        for (int c = 0; c < C_DIM; ++c) { float v = flatT[c][t]; s = fmaf(v, v, s); }
        fnorm_s[t] = s;
    }
    __syncthreads();

    // ---- GEMM 1: 16 rows x 4 consecutive k per thread, prefetched cw ----
    float acc[TR][4];
#pragma unroll
    for (int r = 0; r < TR; ++r)
#pragma unroll
        for (int j = 0; j < 4; ++j) acc[r][j] = 0.f;

    const float4* cbT4 = reinterpret_cast<const float4*>(cbT);  // [c][k/4]
    float4 cwv = cbT4[t];                                       // c = 0
    for (int c = 0; c < C_DIM; ++c) {
        float4 cwn;
        if (c < C_DIM - 1) cwn = cbT4[(c + 1) * (K_CB / 4) + t];
        const float4* fT4 = reinterpret_cast<const float4*>(&flatT[c][0]);
        float4 f0 = fT4[0], f1 = fT4[1], f2 = fT4[2], f3 = fT4[3];
        const float fr[TR] = {f0.x, f0.y, f0.z, f0.w, f1.x, f1.y, f1.z, f1.w,
                              f2.x, f2.y, f2.z, f2.w, f3.x, f3.y, f3.z, f3.w};
#pragma unroll
        for (int r = 0; r < TR; ++r) {
            acc[r][0] = fmaf(fr[r], cwv.x, acc[r][0]);
            acc[r][1] = fmaf(fr[r], cwv.y, acc[r][1]);
            acc[r][2] = fmaf(fr[r], cwv.z, acc[r][2]);
            acc[r][3] = fmaf(fr[r], cwv.w, acc[r][3]);
        }
        cwv = cwn;
    }

    const float4 cn = reinterpret_cast<const float4*>(cnorm)[t];
    const float cna[4] = {cn.x, cn.y, cn.z, cn.w};

    const int lane = t & 63;
    const int wid  = t >> 6;

    // ---- distance, dwordx4 store, per-row argmin (u64 key) ----
#pragma unroll
    for (int r = 0; r < TR; ++r) {
        const float fn = fnorm_s[r];
        unsigned long long best = ~0ull;
        float d0 = fn + cna[0] - 2.f * acc[r][0];
        float d1 = fn + cna[1] - 2.f * acc[r][1];
        float d2 = fn + cna[2] - 2.f * acc[r][2];
        float d3 = fn + cna[3] - 2.f * acc[r][3];
        acc[r][0] = d0; acc[r][1] = d1; acc[r][2] = d2; acc[r][3] = d3;
        float4 dv = {d0, d1, d2, d3};
        reinterpret_cast<float4*>(dist + (size_t)(n0 + r) * K_CB)[t] = dv;
#pragma unroll
        for (int j = 0; j < 4; ++j) {
            unsigned long long key =
                ((unsigned long long)__float_as_uint(acc[r][j]) << 32) | (unsigned)(4 * t + j);
            best = key < best ? key : best;
        }
#pragma unroll
        for (int msk = 1; msk < 64; msk <<= 1) {
            unsigned long long o = __shfl_xor(best, msk, 64);
            best = o < best ? o : best;
        }
        if (lane == 0) redmin[r][wid] = best;
    }
    __syncthreads();
    if (t < TR) {
        unsigned long long v = redmin[t][0];
#pragma unroll
        for (int w = 1; w < 8; ++w) { unsigned long long o = redmin[t][w]; v = o < v ? o : v; }
        m_s[t] = __uint_as_float((unsigned)(v >> 32));
        atomicAdd(&vq0[(unsigned)(v & 0xffffffffu)], 1.0f);
    }
    __syncthreads();

    // ---- stable softmax: e = exp((m - d) * 10) <= 1 ----
#pragma unroll
    for (int r = 0; r < TR; ++r) {
        const float m = m_s[r];
        float s = 0.f;
#pragma unroll
        for (int j = 0; j < 4; ++j) {
            float e = __expf((m - acc[r][j]) * 10.0f);
            acc[r][j] = e;
            s += e;
        }
#pragma unroll
        for (int msk = 1; msk < 64; msk <<= 1) s += __shfl_xor(s, msk, 64);
        if (lane == 0) redsum[r][wid] = s;
    }
    __syncthreads();
    if (t < TR) {
        float s = 0.f;
#pragma unroll
        for (int w = 0; w < 8; ++w) s += redsum[t][w];
        zinv_s[t] = 1.0f / s;
    }
    __syncthreads();

    float inv[TR];
#pragma unroll
    for (int r = 0; r < TR; ++r) inv[r] = zinv_s[r];

    // ---- write normalized prob: lane owns 4 consecutive k-rows, 64B each ----
    const size_t abase = (size_t)b * K_CB * HW_DIM + hw0;
#pragma unroll
    for (int j = 0; j < 4; ++j) {
        const int k = 4 * t + j;
        float4* dst = reinterpret_cast<float4*>(assign + abase + (size_t)k * HW_DIM);
        float4 v0 = { acc[0][j] * inv[0],  acc[1][j] * inv[1],
                      acc[2][j] * inv[2],  acc[3][j] * inv[3]  };
        float4 v1 = { acc[4][j] * inv[4],  acc[5][j] * inv[5],
                      acc[6][j] * inv[6],  acc[7][j] * inv[7]  };
        float4 v2 = { acc[8][j] * inv[8],  acc[9][j] * inv[9],
                      acc[10][j] * inv[10], acc[11][j] * inv[11] };
        float4 v3 = { acc[12][j] * inv[12], acc[13][j] * inv[13],
                      acc[14][j] * inv[14], acc[15][j] * inv[15] };
        dst[0] = v0; dst[1] = v1; dst[2] = v2; dst[3] = v3;
    }
}

// ---------------------------------------------------------------------------
// Kernel C: q_feat = prob @ codebook. WG = (b, 64-hw tile), full k loop,
// NO atomics. Thread: 2 consecutive hw x 8 c = 16 accs, float2 prob loads.
// ---------------------------------------------------------------------------
__global__ __launch_bounds__(256, 8) void vq_qfeat(const float* __restrict__ assign,
                                                   const float* __restrict__ cb,
                                                   float* __restrict__ outf) {
    __shared__ float cb_lds[64][68];               // +4 pad
    const int t   = threadIdx.x;
    const int bid = blockIdx.x;                    // 8 b * 49 tiles
    const int ht  = bid % 49;
    const int b   = bid / 49;
    const int hw0 = ht * 64;
    const int hwp = (t & 31) * 2;                  // hw pair
    const int c0  = (t >> 5) * 8;

    float a00 = 0.f, a01 = 0.f, a02 = 0.f, a03 = 0.f;
    float a04 = 0.f, a05 = 0.f, a06 = 0.f, a07 = 0.f;
    float a10 = 0.f, a11 = 0.f, a12 = 0.f, a13 = 0.f;
    float a14 = 0.f, a15 = 0.f, a16 = 0.f, a17 = 0.f;

    const float* ap = assign + (size_t)b * K_CB * HW_DIM + hw0 + hwp;
    const int srow = t >> 2;
    const int scol = (t & 3) * 16;

    for (int kt = 0; kt < 32; ++kt) {
        const int k0 = kt * 64;
        const float4* src = reinterpret_cast<const float4*>(cb + (size_t)(k0 + srow) * C_DIM + scol);
        float4* dstl = reinterpret_cast<float4*>(&cb_lds[srow][scol]);
#pragma unroll
        for (int q = 0; q < 4; ++q) dstl[q] = src[q];
        __syncthreads();

#pragma unroll 8
        for (int kk = 0; kk < 64; ++kk) {
            const float2 p = *reinterpret_cast<const float2*>(ap + (size_t)(k0 + kk) * HW_DIM);
            const float4 v0 = *reinterpret_cast<const float4*>(&cb_lds[kk][c0]);
            const float4 v1 = *reinterpret_cast<const float4*>(&cb_lds[kk][c0 + 4]);
            a00 = fmaf(p.x, v0.x, a00); a01 = fmaf(p.x, v0.y, a01);
            a02 = fmaf(p.x, v0.z, a02); a03 = fmaf(p.x, v0.w, a03);
            a04 = fmaf(p.x, v1.x, a04); a05 = fmaf(p.x, v1.y, a05);
            a06 = fmaf(p.x, v1.z, a06); a07 = fmaf(p.x, v1.w, a07);
            a10 = fmaf(p.y, v0.x, a10); a11 = fmaf(p.y, v0.y, a11);
            a12 = fmaf(p.y, v0.z, a12); a13 = fmaf(p.y, v0.w, a13);
            a14 = fmaf(p.y, v1.x, a14); a15 = fmaf(p.y, v1.y, a15);
            a16 = fmaf(p.y, v1.z, a16); a17 = fmaf(p.y, v1.w, a17);
        }
        __syncthreads();
    }

    float* ob = outf + ((size_t)b * C_DIM + c0) * HW_DIM + hw0 + hwp;
    float2 s0 = {a00, a10}; *reinterpret_cast<float2*>(ob + 0 * HW_DIM) = s0;
    float2 s1 = {a01, a11}; *reinterpret_cast<float2*>(ob + 1 * HW_DIM) = s1;
    float2 s2 = {a02, a12}; *reinterpret_cast<float2*>(ob + 2 * HW_DIM) = s2;
    float2 s3 = {a03, a13}; *reinterpret_cast<float2*>(ob + 3 * HW_DIM) = s3;
    float2 s4 = {a04, a14}; *reinterpret_cast<float2*>(ob + 4 * HW_DIM) = s4;
    float2 s5 = {a05, a15}; *reinterpret_cast<float2*>(ob + 5 * HW_DIM) = s5;
    float2 s6 = {a06, a16}; *reinterpret_cast<float2*>(ob + 6 * HW_DIM) = s6;
    float2 s7 = {a07, a17}; *reinterpret_cast<float2*>(ob + 7 * HW_DIM) = s7;
}

// ---------------------------------------------------------------------------
extern "C" void kernel_launch(void* const* d_in, const int* in_sizes, int n_in,
                              void* d_out, int out_size, void* d_ws, size_t ws_size,
                              hipStream_t stream) {
    const float* feat = (const float*)d_in[0];
    const float* cb   = (const float*)d_in[1];

    float* out      = (float*)d_out;
    float* out_feat = out;
    float* assign   = out + OUT_FEAT_SZ;
    float* dist     = out + OUT_FEAT_SZ + ASSIGN_SZ;
    float* vq0      = out + OUT_FEAT_SZ + ASSIGN_SZ + DIST_SZ;

    float* cbT   = (float*)d_ws;
    float* cnorm = cbT + (size_t)C_DIM * K_CB;

    vq_prep<<<K_CB / 256, 256, 0, stream>>>(cb, cbT, cnorm, vq0);
    vq_main<<<(B_DIM * HW_DIM) / TR, 512, 0, stream>>>(feat, cbT, cnorm, dist, assign, vq0);
    vq_qfeat<<<B_DIM * (HW_DIM / 64), 256, 0, stream>>>(assign, cb, out_feat);
}

// Round 4
// 873.188 us; speedup vs baseline: 1.7851x; 1.7851x over previous
//
#include <hip/hip_runtime.h>
#include <stddef.h>

#define K_CB   2048
#define C_DIM  64
#define HW_DIM 3136
#define B_DIM  8
#define TR     16
#define TILE_K 128
#define NKT    (K_CB / TILE_K)   // 16

static const size_t OUT_FEAT_SZ = (size_t)B_DIM * C_DIM * HW_DIM;  // 1605632
static const size_t ASSIGN_SZ   = (size_t)B_DIM * K_CB * HW_DIM;   // 51380224
static const size_t DIST_SZ     = (size_t)B_DIM * HW_DIM * K_CB;   // 51380224

// ---------------------------------------------------------------------------
// Kernel A: codebook norms + transpose cbT[c][k] + zero vq0. grid = 8 x 256.
// ---------------------------------------------------------------------------
__global__ __launch_bounds__(256) void vq_prep(const float* __restrict__ cb,
                                               float* __restrict__ cbT,
                                               float* __restrict__ cnorm,
                                               float* __restrict__ vq0) {
    const int k = blockIdx.x * 256 + threadIdx.x;
    const float4* row = reinterpret_cast<const float4*>(cb + (size_t)k * C_DIM);
    float n = 0.f;
#pragma unroll
    for (int i = 0; i < 16; ++i) {
        float4 v = row[i];
        n = fmaf(v.x, v.x, n); n = fmaf(v.y, v.y, n);
        n = fmaf(v.z, v.z, n); n = fmaf(v.w, v.w, n);
        cbT[(size_t)(4 * i + 0) * K_CB + k] = v.x;
        cbT[(size_t)(4 * i + 1) * K_CB + k] = v.y;
        cbT[(size_t)(4 * i + 2) * K_CB + k] = v.z;
        cbT[(size_t)(4 * i + 3) * K_CB + k] = v.w;
    }
    cnorm[k] = n;
    vq0[k] = 0.f;
}

// ---------------------------------------------------------------------------
// Kernel B (fused): distance + argmin/hist + softmax + prob write + q_feat.
// 1024 threads, 16 pixels/WG. Thread owns k = 2t, 2t+1 -> acc[16][2] = 32 VGPR.
// GEMM2 (q_feat) via LDS: per 128-k tile, wave kt writes its p-tile, all
// threads stage cbT tile; thread (r=t&15, c=t>>4) owns one q[r][c] output.
// ---------------------------------------------------------------------------
__global__ __launch_bounds__(1024, 4) void vq_main(const float* __restrict__ feat,
                                                   const float* __restrict__ cbT,
                                                   const float* __restrict__ cnorm,
                                                   float* __restrict__ dist,
                                                   float* __restrict__ assign,
                                                   float* __restrict__ vq0,
                                                   float* __restrict__ outf) {
    const int t   = threadIdx.x;
    const int n0  = blockIdx.x * TR;
    const int b   = n0 / HW_DIM;
    const int hw0 = n0 % HW_DIM;

    __shared__ float flatT[C_DIM][TR];               // 4 KB
    __shared__ float p_lds[TR][TILE_K + 4];          // 8.25 KB, stride 132 (33 quads)
    __shared__ float cbt_lds[C_DIM][TILE_K + 4];     // 33 KB,  stride 132
    __shared__ float fnorm_s[TR];
    __shared__ float m_s[TR];
    __shared__ float zinv_s[TR];
    __shared__ unsigned long long redmin[TR][16];
    __shared__ float redsum[TR][16];

    // stage feat tile (1024 elements, 1 per thread, coalesced 64B per c)
    {
        int c = t >> 4, r = t & 15;
        flatT[c][r] = feat[((size_t)b * C_DIM + c) * HW_DIM + hw0 + r];
    }
    __syncthreads();
    if (t < TR) {
        float s = 0.f;
        for (int c = 0; c < C_DIM; ++c) { float v = flatT[c][t]; s = fmaf(v, v, s); }
        fnorm_s[t] = s;
    }
    __syncthreads();

    // ---- GEMM1: dot(flat_r, cb_k), 16 rows x 2 consecutive k per thread ----
    float acc[TR][2];
#pragma unroll
    for (int r = 0; r < TR; ++r) { acc[r][0] = 0.f; acc[r][1] = 0.f; }

    const float2* cbT2 = reinterpret_cast<const float2*>(cbT);   // [c][k/2]
    float2 cw = cbT2[t];
    for (int c = 0; c < C_DIM; ++c) {
        float2 cwn;
        if (c < C_DIM - 1) cwn = cbT2[(c + 1) * (K_CB / 2) + t];
        const float4* fT4 = reinterpret_cast<const float4*>(&flatT[c][0]);
        float4 f0 = fT4[0], f1 = fT4[1], f2 = fT4[2], f3 = fT4[3];
        const float fr[TR] = {f0.x, f0.y, f0.z, f0.w, f1.x, f1.y, f1.z, f1.w,
                              f2.x, f2.y, f2.z, f2.w, f3.x, f3.y, f3.z, f3.w};
#pragma unroll
        for (int r = 0; r < TR; ++r) {
            acc[r][0] = fmaf(fr[r], cw.x, acc[r][0]);
            acc[r][1] = fmaf(fr[r], cw.y, acc[r][1]);
        }
        cw = cwn;
    }

    const float2 cn2 = reinterpret_cast<const float2*>(cnorm)[t];

    const int lane = t & 63;
    const int wid  = t >> 6;                          // 0..15

    // ---- distance, float2 store (coalesced 8KB/row), per-row argmin ----
#pragma unroll
    for (int r = 0; r < TR; ++r) {
        const float fn = fnorm_s[r];
        float d0 = fn + cn2.x - 2.f * acc[r][0];
        float d1 = fn + cn2.y - 2.f * acc[r][1];
        acc[r][0] = d0; acc[r][1] = d1;
        float2 dv = {d0, d1};
        reinterpret_cast<float2*>(dist + (size_t)(n0 + r) * K_CB)[t] = dv;
        unsigned long long k0 =
            ((unsigned long long)__float_as_uint(d0) << 32) | (unsigned)(2 * t);
        unsigned long long k1 =
            ((unsigned long long)__float_as_uint(d1) << 32) | (unsigned)(2 * t + 1);
        unsigned long long best = k0 < k1 ? k0 : k1;
#pragma unroll
        for (int msk = 1; msk < 64; msk <<= 1) {
            unsigned long long o = __shfl_xor(best, msk, 64);
            best = o < best ? o : best;
        }
        if (lane == 0) redmin[r][wid] = best;
    }
    __syncthreads();
    if (t < TR) {
        unsigned long long v = redmin[t][0];
#pragma unroll
        for (int w = 1; w < 16; ++w) { unsigned long long o = redmin[t][w]; v = o < v ? o : v; }
        m_s[t] = __uint_as_float((unsigned)(v >> 32));
        atomicAdd(&vq0[(unsigned)(v & 0xffffffffu)], 1.0f);
    }
    __syncthreads();

    // ---- stable softmax: e = exp((m - d) * 10) <= 1 ----
#pragma unroll
    for (int r = 0; r < TR; ++r) {
        const float m = m_s[r];
        float e0 = __expf((m - acc[r][0]) * 10.0f);
        float e1 = __expf((m - acc[r][1]) * 10.0f);
        acc[r][0] = e0; acc[r][1] = e1;
        float s = e0 + e1;
#pragma unroll
        for (int msk = 1; msk < 64; msk <<= 1) s += __shfl_xor(s, msk, 64);
        if (lane == 0) redsum[r][wid] = s;
    }
    __syncthreads();
    if (t < TR) {
        float s = 0.f;
#pragma unroll
        for (int w = 0; w < 16; ++w) s += redsum[t][w];
        zinv_s[t] = 1.0f / s;
    }
    __syncthreads();

    float inv[TR];
#pragma unroll
    for (int r = 0; r < TR; ++r) inv[r] = zinv_s[r];

    // ---- write normalized prob: 2 k-rows per thread, 64B each ----
    const size_t abase = (size_t)b * K_CB * HW_DIM + hw0;
#pragma unroll
    for (int j = 0; j < 2; ++j) {
        float4* dst = reinterpret_cast<float4*>(assign + abase + (size_t)(2 * t + j) * HW_DIM);
        float4 v0 = { acc[0][j] * inv[0],  acc[1][j] * inv[1],
                      acc[2][j] * inv[2],  acc[3][j] * inv[3]  };
        float4 v1 = { acc[4][j] * inv[4],  acc[5][j] * inv[5],
                      acc[6][j] * inv[6],  acc[7][j] * inv[7]  };
        float4 v2 = { acc[8][j] * inv[8],  acc[9][j] * inv[9],
                      acc[10][j] * inv[10], acc[11][j] * inv[11] };
        float4 v3 = { acc[12][j] * inv[12], acc[13][j] * inv[13],
                      acc[14][j] * inv[14], acc[15][j] * inv[15] };
        dst[0] = v0; dst[1] = v1; dst[2] = v2; dst[3] = v3;
    }

    // ---- GEMM2 (fused q_feat): q[r][c] = sum_k p[r][k] * cb[k][c] ----
    const int r2 = t & 15;
    const int c2 = t >> 4;                            // 0..63
    const int srow = t >> 4;                          // cbt staging row
    const int sk8  = (t & 15) * 8;                    // 8 floats per thread
    float accq = 0.f;

    // preload tile 0 into regs
    float4 stg0, stg1;
    {
        const float* g = cbT + (size_t)srow * K_CB + sk8;
        stg0 = *reinterpret_cast<const float4*>(g);
        stg1 = *reinterpret_cast<const float4*>(g + 4);
    }

    for (int kt = 0; kt < NKT; ++kt) {
        // write staged cbT tile to LDS
        *reinterpret_cast<float4*>(&cbt_lds[srow][sk8])     = stg0;
        *reinterpret_cast<float4*>(&cbt_lds[srow][sk8 + 4]) = stg1;
        // wave kt writes its normalized p tile [16][128]
        if (wid == kt) {
            const int tl = 2 * (t & 63);              // k-local index
#pragma unroll
            for (int r = 0; r < TR; ++r) {
                float2 pv = { acc[r][0] * inv[r], acc[r][1] * inv[r] };
                *reinterpret_cast<float2*>(&p_lds[r][tl]) = pv;
            }
        }
        __syncthreads();
        // prefetch next tile (overlaps GEMM2)
        if (kt + 1 < NKT) {
            const float* g = cbT + (size_t)srow * K_CB + (kt + 1) * TILE_K + sk8;
            stg0 = *reinterpret_cast<const float4*>(g);
            stg1 = *reinterpret_cast<const float4*>(g + 4);
        }
        // inner product over the 128-k tile
#pragma unroll 8
        for (int k4 = 0; k4 < TILE_K / 4; ++k4) {
            float4 pv = *reinterpret_cast<const float4*>(&p_lds[r2][4 * k4]);
            float4 cv = *reinterpret_cast<const float4*>(&cbt_lds[c2][4 * k4]);
            accq = fmaf(pv.x, cv.x, accq);
            accq = fmaf(pv.y, cv.y, accq);
            accq = fmaf(pv.z, cv.z, accq);
            accq = fmaf(pv.w, cv.w, accq);
        }
        __syncthreads();
    }

    // out_feat store: 16 consecutive hw per (c) -> 64B chunks
    outf[((size_t)b * C_DIM + c2) * HW_DIM + hw0 + r2] = accq;
}

// ---------------------------------------------------------------------------
extern "C" void kernel_launch(void* const* d_in, const int* in_sizes, int n_in,
                              void* d_out, int out_size, void* d_ws, size_t ws_size,
                              hipStream_t stream) {
    const float* feat = (const float*)d_in[0];
    const float* cb   = (const float*)d_in[1];

    float* out      = (float*)d_out;
    float* out_feat = out;
    float* assign   = out + OUT_FEAT_SZ;
    float* dist     = out + OUT_FEAT_SZ + ASSIGN_SZ;
    float* vq0      = out + OUT_FEAT_SZ + ASSIGN_SZ + DIST_SZ;

    float* cbT   = (float*)d_ws;
    float* cnorm = cbT + (size_t)C_DIM * K_CB;

    vq_prep<<<K_CB / 256, 256, 0, stream>>>(cb, cbT, cnorm, vq0);
    vq_main<<<(B_DIM * HW_DIM) / TR, 1024, 0, stream>>>(feat, cbT, cnorm, dist, assign,
                                                        vq0, out_feat);
}